// Round 2
// baseline (291.546 us; speedup 1.0000x reference)
//
#include <hip/hip_runtime.h>
#include <math.h>

// Fused self-attention, B=8, S=2048, D=64 fp32; outputs context [8,2048,64] and
// full attention filter [8,2048,2048].
//
// Round-8: keep stores out of the vmcnt critical path + kill atomics.
//   - attn_emit: software-pipelined. K/VT/mask fragments for iteration kb+1
//     are loaded into REGISTERS at the top of iteration kb, BEFORE the Filt
//     stores are issued. vmcnt is in-order, so any MFMA's load-wait now only
//     drains loads issued before the previous stores -> Filt stores stay in
//     flight across the whole loop (T4 counted-vmcnt effect). VT comes from
//     registers (no LDS staging); only the tiny per-wave P park uses LDS.
//   - Ctx atomics removed: emit writes per-split partials Opart[4][8][2048][64]
//     (plain stores, L2-resident 16 MiB); new attn_ctx kernel reduces 4 -> Ctx.
//     Prep no longer zeroes Ctx.
//   - Swapped-operand QK^T (C[key][query]) as in round-7: dwordx4 nontemporal
//     Filt stores, 2-shuffle row-sum, scalar invl.
//   - softmax temperature folded into Q->bf16 conversion (x2^-3 exact).

typedef short bf16x8 __attribute__((ext_vector_type(8)));
typedef short bf16x4 __attribute__((ext_vector_type(4)));
typedef float f32x4 __attribute__((ext_vector_type(4)));

#define BATCH 8
#define SDIM 2048
#define DDIM 64
#define KBLK 64
#define NBLK (SDIM / KBLK)      // 32
#define KSPLIT 4
#define BPW (NBLK / KSPLIT)     // 8 key-blocks per WG
#define NROWS (BATCH * SDIM)    // 16384
#define SCALE 0.125f
#define KSTR 72                 // LDS row stride in shorts (144 B, 16B-aligned)

__device__ __forceinline__ short f2bf(float f) {
    unsigned x = __float_as_uint(f);
    x = (x + 0x7fffu + ((x >> 16) & 1u)) >> 16;   // RNE
    return (short)x;
}
__device__ __forceinline__ float fidx(const float4& v, int i) {
    return ((const float*)&v)[i];
}

// ======== K0: K->bf16, V->bf16 transposed.  256 WGs ========
__global__ __launch_bounds__(256, 4)
void attn_prep(const float* __restrict__ Kg, const float* __restrict__ Vg,
               short* __restrict__ Kbf, short* __restrict__ VTbf)
{
    __shared__ short VTlds[DDIM][KSTR];

    const int wg = blockIdx.x;           // 256 = 8 batches x 32 key-blocks
    const int b = wg & 7;
    const int kbase = (wg >> 3) * KBLK;
    const int tid = threadIdx.x;

    const float* Kb = Kg + (size_t)b * SDIM * DDIM;
    const float* Vb = Vg + (size_t)b * SDIM * DDIM;

    // K convert: thread t -> key=t>>2, 16 d's
    {
        const int key = tid >> 2, doff = (tid & 3) * 16;
        const float* src = Kb + (size_t)(kbase + key) * DDIM + doff;
        float4 f0 = *(const float4*)(src);
        float4 f1 = *(const float4*)(src + 4);
        float4 f2 = *(const float4*)(src + 8);
        float4 f3 = *(const float4*)(src + 12);
        bf16x8 p0, p1;
        p0[0]=f2bf(f0.x); p0[1]=f2bf(f0.y); p0[2]=f2bf(f0.z); p0[3]=f2bf(f0.w);
        p0[4]=f2bf(f1.x); p0[5]=f2bf(f1.y); p0[6]=f2bf(f1.z); p0[7]=f2bf(f1.w);
        p1[0]=f2bf(f2.x); p1[1]=f2bf(f2.y); p1[2]=f2bf(f2.z); p1[3]=f2bf(f2.w);
        p1[4]=f2bf(f3.x); p1[5]=f2bf(f3.y); p1[6]=f2bf(f3.z); p1[7]=f2bf(f3.w);
        short* dst = Kbf + ((size_t)b * SDIM + kbase + key) * DDIM + doff;
        *(bf16x8*)dst = p0;
        *(bf16x8*)(dst + 8) = p1;
    }

    // V transpose via LDS: thread t loads 4 keys x 4 d's, writes transposed
    {
        const int sv_d0 = (tid & 15) * 4, sv_k0 = (tid >> 4) * 4;
        float4 vreg[4];
        #pragma unroll
        for (int i = 0; i < 4; ++i)
            vreg[i] = *(const float4*)(Vb + (size_t)(kbase + sv_k0 + i) * DDIM + sv_d0);
        #pragma unroll
        for (int dd = 0; dd < 4; ++dd) {
            bf16x4 pv;
            pv[0] = f2bf(fidx(vreg[0], dd));
            pv[1] = f2bf(fidx(vreg[1], dd));
            pv[2] = f2bf(fidx(vreg[2], dd));
            pv[3] = f2bf(fidx(vreg[3], dd));
            *(bf16x4*)&VTlds[sv_d0 + dd][sv_k0] = pv;
        }
    }
    __syncthreads();
    {
        const int d = tid >> 2, koff = (tid & 3) * 16;
        bf16x8 a = *(const bf16x8*)&VTlds[d][koff];
        bf16x8 c = *(const bf16x8*)&VTlds[d][koff + 8];
        short* dst = VTbf + ((size_t)b * DDIM + d) * SDIM + kbase + koff;
        *(bf16x8*)dst = a;
        *(bf16x8*)(dst + 8) = c;
    }
}

// ============ K1: partial row sums (no LDS, no barriers) ============
// Swapped MFMA: C[key=quad*4+r][query=col]; lsum is per-lane scalar.
__global__ __launch_bounds__(256, 4)
void attn_stats(const short* __restrict__ Kbf, const float* __restrict__ Qg,
                const int* __restrict__ Mg, float* __restrict__ part)
{
    const int wg = blockIdx.x;
    const int b = wg & 7;
    const int qt = (wg >> 3) & 31;
    const int sp = wg >> 8;
    const int tid = threadIdx.x;
    const int w = tid >> 6, lane = tid & 63, col = lane & 15, quad = lane >> 4;

    // persistent Q fragment (used as B operand); temperature folded in (exact)
    bf16x8 aq[2];
    {
        const float* qsrc = Qg + ((size_t)b * SDIM + qt * 64 + w * 16 + col) * DDIM + quad * 8;
        #pragma unroll
        for (int c = 0; c < 2; ++c) {
            float4 f0 = *(const float4*)(qsrc + c * 32);
            float4 f1 = *(const float4*)(qsrc + c * 32 + 4);
            bf16x8 a;
            a[0]=f2bf(f0.x*SCALE); a[1]=f2bf(f0.y*SCALE); a[2]=f2bf(f0.z*SCALE); a[3]=f2bf(f0.w*SCALE);
            a[4]=f2bf(f1.x*SCALE); a[5]=f2bf(f1.y*SCALE); a[6]=f2bf(f1.z*SCALE); a[7]=f2bf(f1.w*SCALE);
            aq[c] = a;
        }
    }

    const int kb0 = sp * BPW * KBLK;
    const short* Kb = Kbf + (size_t)b * SDIM * DDIM;
    const int*   Mb = Mg + (size_t)b * SDIM;

    float lsum = 0.0f;
    for (int kb = 0; kb < BPW; ++kb) {
        const int kbase = kb0 + kb * KBLK;
        bf16x8 kf[4][2];
        #pragma unroll
        for (int t = 0; t < 4; ++t) {
            const short* ks = Kb + (size_t)(kbase + t * 16 + col) * DDIM + quad * 8;
            kf[t][0] = *(const bf16x8*)ks;
            kf[t][1] = *(const bf16x8*)(ks + 32);
        }
        #pragma unroll
        for (int t = 0; t < 4; ++t) {
            f32x4 acc = {0.f, 0.f, 0.f, 0.f};
            acc = __builtin_amdgcn_mfma_f32_16x16x32_bf16(kf[t][0], aq[0], acc, 0, 0, 0);
            acc = __builtin_amdgcn_mfma_f32_16x16x32_bf16(kf[t][1], aq[1], acc, 0, 0, 0);
            int4 mq = *(const int4*)(Mb + kbase + t * 16 + quad * 4);
            lsum += mq.x ? 0.0f : __expf(acc[0]);
            lsum += mq.y ? 0.0f : __expf(acc[1]);
            lsum += mq.z ? 0.0f : __expf(acc[2]);
            lsum += mq.w ? 0.0f : __expf(acc[3]);
        }
    }

    // each lane has a quarter of this query's keys; sum across quads
    lsum += __shfl_xor(lsum, 16);
    lsum += __shfl_xor(lsum, 32);
    if (quad == 0)
        part[(size_t)sp * NROWS + (size_t)b * SDIM + qt * 64 + w * 16 + col] = lsum;
}

// ======= K2: emit filter + per-split context partials (pipelined) =======
__global__ __launch_bounds__(256, 4)
void attn_emit(const short* __restrict__ Kbf, const short* __restrict__ VTbf,
               const float* __restrict__ Qg, const int* __restrict__ Mg,
               const float* __restrict__ part, float* __restrict__ Opart,
               float* __restrict__ Filt)
{
    __shared__ short Plds[4][16][KSTR];   // per-wave bf16 P tile [q=16][k=64]

    const int wg = blockIdx.x;
    const int b = wg & 7;
    const int qt = (wg >> 3) & 31;
    const int sp = wg >> 8;
    const int tid = threadIdx.x;
    const int w = tid >> 6, lane = tid & 63, col = lane & 15, quad = lane >> 4;

    const int*   Mb = Mg + (size_t)b * SDIM;
    const short* Kb = Kbf + (size_t)b * SDIM * DDIM;
    const short* VTb = VTbf + (size_t)b * DDIM * SDIM;
    float* Filtb = Filt + (size_t)b * SDIM * SDIM;

    bf16x8 aq[2];
    {
        const float* qsrc = Qg + ((size_t)b * SDIM + qt * 64 + w * 16 + col) * DDIM + quad * 8;
        #pragma unroll
        for (int c = 0; c < 2; ++c) {
            float4 f0 = *(const float4*)(qsrc + c * 32);
            float4 f1 = *(const float4*)(qsrc + c * 32 + 4);
            bf16x8 a;
            a[0]=f2bf(f0.x*SCALE); a[1]=f2bf(f0.y*SCALE); a[2]=f2bf(f0.z*SCALE); a[3]=f2bf(f0.w*SCALE);
            a[4]=f2bf(f1.x*SCALE); a[5]=f2bf(f1.y*SCALE); a[6]=f2bf(f1.z*SCALE); a[7]=f2bf(f1.w*SCALE);
            aq[c] = a;
        }
    }

    // merge folded in: invl for THIS lane's query row (query = col)
    float invl;
    {
        const size_t row = (size_t)b * SDIM + qt * 64 + w * 16 + col;
        invl = 1.0f / (part[row] + part[NROWS + row] +
                       part[2 * NROWS + row] + part[3 * NROWS + row]);
    }

    const int kb0 = sp * BPW * KBLK;

    f32x4 Oacc[4];
    #pragma unroll
    for (int dt = 0; dt < 4; ++dt) Oacc[dt] = (f32x4){0.f, 0.f, 0.f, 0.f};

    // ---- prologue: load fragments for kb=0 into register buffer A ----
    bf16x8 kfA[4][2], vtA[2][4];
    int4 mqA[4];
    {
        #pragma unroll
        for (int t = 0; t < 4; ++t) {
            const short* ks = Kb + (size_t)(kb0 + t * 16 + col) * DDIM + quad * 8;
            kfA[t][0] = *(const bf16x8*)ks;
            kfA[t][1] = *(const bf16x8*)(ks + 32);
        }
        #pragma unroll
        for (int c = 0; c < 2; ++c)
            #pragma unroll
            for (int dt = 0; dt < 4; ++dt)
                vtA[c][dt] = *(const bf16x8*)(VTb + (size_t)(dt * 16 + col) * SDIM + kb0 + c * 32 + quad * 8);
        #pragma unroll
        for (int t = 0; t < 4; ++t)
            mqA[t] = *(const int4*)(Mb + kb0 + t * 16 + quad * 4);
    }

    for (int kb = 0; kb < BPW; ++kb) {
        const int kbase = kb0 + kb * KBLK;

        // ---- issue next-iteration loads FIRST (before any store this iter) ----
        bf16x8 kfB[4][2], vtB[2][4];
        int4 mqB[4];
        const bool has_next = (kb + 1 < BPW);
        if (has_next) {
            const int kn = kbase + KBLK;
            #pragma unroll
            for (int t = 0; t < 4; ++t) {
                const short* ks = Kb + (size_t)(kn + t * 16 + col) * DDIM + quad * 8;
                kfB[t][0] = *(const bf16x8*)ks;
                kfB[t][1] = *(const bf16x8*)(ks + 32);
            }
            #pragma unroll
            for (int c = 0; c < 2; ++c)
                #pragma unroll
                for (int dt = 0; dt < 4; ++dt)
                    vtB[c][dt] = *(const bf16x8*)(VTb + (size_t)(dt * 16 + col) * SDIM + kn + c * 32 + quad * 8);
            #pragma unroll
            for (int t = 0; t < 4; ++t)
                mqB[t] = *(const int4*)(Mb + kn + t * 16 + quad * 4);
        }

        // ---- QK^T (swapped): lane -> query=col, keys kbase+t*16+quad*4+r ----
        #pragma unroll
        for (int t = 0; t < 4; ++t) {
            f32x4 acc = {0.f, 0.f, 0.f, 0.f};
            acc = __builtin_amdgcn_mfma_f32_16x16x32_bf16(kfA[t][0], aq[0], acc, 0, 0, 0);
            acc = __builtin_amdgcn_mfma_f32_16x16x32_bf16(kfA[t][1], aq[1], acc, 0, 0, 0);
            f32x4 p4;
            p4[0] = mqA[t].x ? 0.0f : __expf(acc[0]) * invl;
            p4[1] = mqA[t].y ? 0.0f : __expf(acc[1]) * invl;
            p4[2] = mqA[t].z ? 0.0f : __expf(acc[2]) * invl;
            p4[3] = mqA[t].w ? 0.0f : __expf(acc[3]) * invl;
            // 4 consecutive keys of one query row -> dwordx4 nontemporal store.
            // Issued AFTER the next-iter loads: no later load-wait drains it.
            f32x4* fdst = (f32x4*)&Filtb[(size_t)(qt * 64 + w * 16 + col) * SDIM + kbase + t * 16 + quad * 4];
            __builtin_nontemporal_store(p4, fdst);
            bf16x4 pb;
            pb[0] = f2bf(p4[0]); pb[1] = f2bf(p4[1]);
            pb[2] = f2bf(p4[2]); pb[3] = f2bf(p4[3]);
            *(bf16x4*)&Plds[w][col][t * 16 + quad * 4] = pb;   // per-wave park
        }

        // ---- O += P * V  (VT from registers; zero VMEM waits here) ----
        #pragma unroll
        for (int c = 0; c < 2; ++c) {
            bf16x8 ap = *(const bf16x8*)&Plds[w][col][c * 32 + quad * 8];
            #pragma unroll
            for (int dt = 0; dt < 4; ++dt)
                Oacc[dt] = __builtin_amdgcn_mfma_f32_16x16x32_bf16(ap, vtA[c][dt], Oacc[dt], 0, 0, 0);
        }

        // ---- rotate register buffers ----
        if (has_next) {
            #pragma unroll
            for (int t = 0; t < 4; ++t) { kfA[t][0] = kfB[t][0]; kfA[t][1] = kfB[t][1]; mqA[t] = mqB[t]; }
            #pragma unroll
            for (int c = 0; c < 2; ++c)
                #pragma unroll
                for (int dt = 0; dt < 4; ++dt) vtA[c][dt] = vtB[c][dt];
        }
    }

    // per-split context partial (plain stores; reduced by attn_ctx)
    float* Ob = Opart + ((size_t)sp * NROWS + (size_t)b * SDIM) * DDIM;
    #pragma unroll
    for (int dt = 0; dt < 4; ++dt) {
        #pragma unroll
        for (int r = 0; r < 4; ++r)
            Ob[(size_t)(qt * 64 + w * 16 + quad * 4 + r) * DDIM + dt * 16 + col] = Oacc[dt][r];
    }
}

// ===================== K3: reduce 4 split-partials -> Ctx =====================
__global__ __launch_bounds__(256)
void attn_ctx(const float* __restrict__ Opart, float* __restrict__ Ctx)
{
    const size_t t = (size_t)blockIdx.x * 256 + threadIdx.x;   // one float4 each
    const size_t Qn = (size_t)NROWS * DDIM / 4;                // 262144
    const f32x4* op = (const f32x4*)Opart;
    f32x4 s0 = op[t] + op[Qn + t];
    f32x4 s1 = op[2 * Qn + t] + op[3 * Qn + t];
    ((f32x4*)Ctx)[t] = s0 + s1;
}

extern "C" void kernel_launch(void* const* d_in, const int* in_sizes, int n_in,
                              void* d_out, int out_size, void* d_ws, size_t ws_size,
                              hipStream_t stream) {
    // setup_inputs order: key, query, value, query_attention_mask
    const float* Kg = (const float*)d_in[0];
    const float* Qg = (const float*)d_in[1];
    const float* Vg = (const float*)d_in[2];
    const int*   Mg = (const int*)d_in[3];
    float* Ctx  = (float*)d_out;                                   // [8,2048,64]
    float* Filt = (float*)d_out + (size_t)BATCH * SDIM * DDIM;     // [8,2048,2048]

    // workspace: Kbf 2 MB | VTbf 2 MB | part 256 KB | Opart 16 MB
    short* Kbf  = (short*)d_ws;                                    // [8][2048][64] bf16
    short* VTbf = Kbf + (size_t)BATCH * SDIM * DDIM;               // [8][64][2048] bf16
    float* part = (float*)(VTbf + (size_t)BATCH * DDIM * SDIM);    // [4][16384]
    float* Opart = part + (size_t)KSPLIT * NROWS;                  // [4][16384][64]

    attn_prep<<<dim3(BATCH * NBLK), dim3(256), 0, stream>>>(Kg, Vg, Kbf, VTbf);
    // 8 batches x 32 qtiles x 4 key-splits = 1024 WGs (sp = wg>>8 decode)
    attn_stats<<<dim3(BATCH * NBLK * KSPLIT), dim3(256), 0, stream>>>(Kbf, Qg, Mg, part);
    attn_emit<<<dim3(BATCH * NBLK * KSPLIT), dim3(256), 0, stream>>>(Kbf, VTbf, Qg, Mg, part, Opart, Filt);
    attn_ctx<<<dim3(NROWS * DDIM / 4 / 256), dim3(256), 0, stream>>>(Opart, Ctx);
}

// Round 3
// 242.071 us; speedup vs baseline: 1.2044x; 1.2044x over previous
//
#include <hip/hip_runtime.h>
#include <math.h>

// Fused self-attention, B=8, S=2048, D=64 fp32; outputs context [8,2048,64] and
// full attention filter [8,2048,2048].
//
// Round-9: round-8's pipeline idea, but within the register budget.
//   Round-8 post-mortem: double-buffering K+VT+mask (+48 VGPR) spilled to
//   scratch (WRITE_SIZE 326 MB vs 131 MB payload) and tanked occupancy.
//   Round-9 keeps ONLY K double-buffered (the tightest MFMA dependency);
//   VT and mask are single-buffered but their loads are issued BEFORE the
//   Filt stores of the same iteration, so (in-order vmcnt):
//     - QK^T waits on kfA loaded 2 iterations ago -> drains stores(kb-2) only
//     - exp waits on mq(kb) issued before stores(kb-1)... -> >=1 iter slack
//     - PV waits on vt(kb) with vmcnt(4): stores(kb) stay in flight
//   Stores never gate the iteration that issued them.
//   - Ctx atomics removed (round-8): per-split partials + attn_ctx reduction.
//   - Swapped-operand QK^T (C[key][query]): dwordx4 nontemporal Filt stores.
//   - softmax temperature folded into Q->bf16 conversion (x2^-3 exact).

typedef short bf16x8 __attribute__((ext_vector_type(8)));
typedef short bf16x4 __attribute__((ext_vector_type(4)));
typedef float f32x4 __attribute__((ext_vector_type(4)));

#define BATCH 8
#define SDIM 2048
#define DDIM 64
#define KBLK 64
#define NBLK (SDIM / KBLK)      // 32
#define KSPLIT 4
#define BPW (NBLK / KSPLIT)     // 8 key-blocks per WG
#define NROWS (BATCH * SDIM)    // 16384
#define SCALE 0.125f
#define KSTR 72                 // LDS row stride in shorts (144 B, 16B-aligned)

__device__ __forceinline__ short f2bf(float f) {
    unsigned x = __float_as_uint(f);
    x = (x + 0x7fffu + ((x >> 16) & 1u)) >> 16;   // RNE
    return (short)x;
}
__device__ __forceinline__ float fidx(const float4& v, int i) {
    return ((const float*)&v)[i];
}

// ======== K0: K->bf16, V->bf16 transposed.  256 WGs ========
__global__ __launch_bounds__(256, 4)
void attn_prep(const float* __restrict__ Kg, const float* __restrict__ Vg,
               short* __restrict__ Kbf, short* __restrict__ VTbf)
{
    __shared__ short VTlds[DDIM][KSTR];

    const int wg = blockIdx.x;           // 256 = 8 batches x 32 key-blocks
    const int b = wg & 7;
    const int kbase = (wg >> 3) * KBLK;
    const int tid = threadIdx.x;

    const float* Kb = Kg + (size_t)b * SDIM * DDIM;
    const float* Vb = Vg + (size_t)b * SDIM * DDIM;

    // K convert: thread t -> key=t>>2, 16 d's
    {
        const int key = tid >> 2, doff = (tid & 3) * 16;
        const float* src = Kb + (size_t)(kbase + key) * DDIM + doff;
        float4 f0 = *(const float4*)(src);
        float4 f1 = *(const float4*)(src + 4);
        float4 f2 = *(const float4*)(src + 8);
        float4 f3 = *(const float4*)(src + 12);
        bf16x8 p0, p1;
        p0[0]=f2bf(f0.x); p0[1]=f2bf(f0.y); p0[2]=f2bf(f0.z); p0[3]=f2bf(f0.w);
        p0[4]=f2bf(f1.x); p0[5]=f2bf(f1.y); p0[6]=f2bf(f1.z); p0[7]=f2bf(f1.w);
        p1[0]=f2bf(f2.x); p1[1]=f2bf(f2.y); p1[2]=f2bf(f2.z); p1[3]=f2bf(f2.w);
        p1[4]=f2bf(f3.x); p1[5]=f2bf(f3.y); p1[6]=f2bf(f3.z); p1[7]=f2bf(f3.w);
        short* dst = Kbf + ((size_t)b * SDIM + kbase + key) * DDIM + doff;
        *(bf16x8*)dst = p0;
        *(bf16x8*)(dst + 8) = p1;
    }

    // V transpose via LDS: thread t loads 4 keys x 4 d's, writes transposed
    {
        const int sv_d0 = (tid & 15) * 4, sv_k0 = (tid >> 4) * 4;
        float4 vreg[4];
        #pragma unroll
        for (int i = 0; i < 4; ++i)
            vreg[i] = *(const float4*)(Vb + (size_t)(kbase + sv_k0 + i) * DDIM + sv_d0);
        #pragma unroll
        for (int dd = 0; dd < 4; ++dd) {
            bf16x4 pv;
            pv[0] = f2bf(fidx(vreg[0], dd));
            pv[1] = f2bf(fidx(vreg[1], dd));
            pv[2] = f2bf(fidx(vreg[2], dd));
            pv[3] = f2bf(fidx(vreg[3], dd));
            *(bf16x4*)&VTlds[sv_d0 + dd][sv_k0] = pv;
        }
    }
    __syncthreads();
    {
        const int d = tid >> 2, koff = (tid & 3) * 16;
        bf16x8 a = *(const bf16x8*)&VTlds[d][koff];
        bf16x8 c = *(const bf16x8*)&VTlds[d][koff + 8];
        short* dst = VTbf + ((size_t)b * DDIM + d) * SDIM + kbase + koff;
        *(bf16x8*)dst = a;
        *(bf16x8*)(dst + 8) = c;
    }
}

// ============ K1: partial row sums (no LDS, no barriers) ============
// Swapped MFMA: C[key=quad*4+r][query=col]; lsum is per-lane scalar.
__global__ __launch_bounds__(256, 4)
void attn_stats(const short* __restrict__ Kbf, const float* __restrict__ Qg,
                const int* __restrict__ Mg, float* __restrict__ part)
{
    const int wg = blockIdx.x;
    const int b = wg & 7;
    const int qt = (wg >> 3) & 31;
    const int sp = wg >> 8;
    const int tid = threadIdx.x;
    const int w = tid >> 6, lane = tid & 63, col = lane & 15, quad = lane >> 4;

    // persistent Q fragment (used as B operand); temperature folded in (exact)
    bf16x8 aq[2];
    {
        const float* qsrc = Qg + ((size_t)b * SDIM + qt * 64 + w * 16 + col) * DDIM + quad * 8;
        #pragma unroll
        for (int c = 0; c < 2; ++c) {
            float4 f0 = *(const float4*)(qsrc + c * 32);
            float4 f1 = *(const float4*)(qsrc + c * 32 + 4);
            bf16x8 a;
            a[0]=f2bf(f0.x*SCALE); a[1]=f2bf(f0.y*SCALE); a[2]=f2bf(f0.z*SCALE); a[3]=f2bf(f0.w*SCALE);
            a[4]=f2bf(f1.x*SCALE); a[5]=f2bf(f1.y*SCALE); a[6]=f2bf(f1.z*SCALE); a[7]=f2bf(f1.w*SCALE);
            aq[c] = a;
        }
    }

    const int kb0 = sp * BPW * KBLK;
    const short* Kb = Kbf + (size_t)b * SDIM * DDIM;
    const int*   Mb = Mg + (size_t)b * SDIM;

    float lsum = 0.0f;
    for (int kb = 0; kb < BPW; ++kb) {
        const int kbase = kb0 + kb * KBLK;
        bf16x8 kf[4][2];
        #pragma unroll
        for (int t = 0; t < 4; ++t) {
            const short* ks = Kb + (size_t)(kbase + t * 16 + col) * DDIM + quad * 8;
            kf[t][0] = *(const bf16x8*)ks;
            kf[t][1] = *(const bf16x8*)(ks + 32);
        }
        #pragma unroll
        for (int t = 0; t < 4; ++t) {
            f32x4 acc = {0.f, 0.f, 0.f, 0.f};
            acc = __builtin_amdgcn_mfma_f32_16x16x32_bf16(kf[t][0], aq[0], acc, 0, 0, 0);
            acc = __builtin_amdgcn_mfma_f32_16x16x32_bf16(kf[t][1], aq[1], acc, 0, 0, 0);
            int4 mq = *(const int4*)(Mb + kbase + t * 16 + quad * 4);
            lsum += mq.x ? 0.0f : __expf(acc[0]);
            lsum += mq.y ? 0.0f : __expf(acc[1]);
            lsum += mq.z ? 0.0f : __expf(acc[2]);
            lsum += mq.w ? 0.0f : __expf(acc[3]);
        }
    }

    // each lane has a quarter of this query's keys; sum across quads
    lsum += __shfl_xor(lsum, 16);
    lsum += __shfl_xor(lsum, 32);
    if (quad == 0)
        part[(size_t)sp * NROWS + (size_t)b * SDIM + qt * 64 + w * 16 + col] = lsum;
}

// ======= K2: emit filter + per-split context partials (slim pipeline) =======
__global__ __launch_bounds__(256, 4)
void attn_emit(const short* __restrict__ Kbf, const short* __restrict__ VTbf,
               const float* __restrict__ Qg, const int* __restrict__ Mg,
               const float* __restrict__ part, float* __restrict__ Opart,
               float* __restrict__ Filt)
{
    __shared__ short Plds[4][16][KSTR];   // per-wave bf16 P tile [q=16][k=64]

    const int wg = blockIdx.x;
    const int b = wg & 7;
    const int qt = (wg >> 3) & 31;
    const int sp = wg >> 8;
    const int tid = threadIdx.x;
    const int w = tid >> 6, lane = tid & 63, col = lane & 15, quad = lane >> 4;

    const int*   Mb = Mg + (size_t)b * SDIM;
    const short* Kb = Kbf + (size_t)b * SDIM * DDIM;
    const short* VTb = VTbf + (size_t)b * DDIM * SDIM;
    float* Filtb = Filt + (size_t)b * SDIM * SDIM;

    bf16x8 aq[2];
    {
        const float* qsrc = Qg + ((size_t)b * SDIM + qt * 64 + w * 16 + col) * DDIM + quad * 8;
        #pragma unroll
        for (int c = 0; c < 2; ++c) {
            float4 f0 = *(const float4*)(qsrc + c * 32);
            float4 f1 = *(const float4*)(qsrc + c * 32 + 4);
            bf16x8 a;
            a[0]=f2bf(f0.x*SCALE); a[1]=f2bf(f0.y*SCALE); a[2]=f2bf(f0.z*SCALE); a[3]=f2bf(f0.w*SCALE);
            a[4]=f2bf(f1.x*SCALE); a[5]=f2bf(f1.y*SCALE); a[6]=f2bf(f1.z*SCALE); a[7]=f2bf(f1.w*SCALE);
            aq[c] = a;
        }
    }

    // merge folded in: invl for THIS lane's query row (query = col)
    float invl;
    {
        const size_t row = (size_t)b * SDIM + qt * 64 + w * 16 + col;
        invl = 1.0f / (part[row] + part[NROWS + row] +
                       part[2 * NROWS + row] + part[3 * NROWS + row]);
    }

    const int kb0 = sp * BPW * KBLK;

    f32x4 Oacc[4];
    #pragma unroll
    for (int dt = 0; dt < 4; ++dt) Oacc[dt] = (f32x4){0.f, 0.f, 0.f, 0.f};

    // ---- prologue: K fragments for kb=0 (the only double-buffered operand) ----
    bf16x8 kfA[4][2];
    #pragma unroll
    for (int t = 0; t < 4; ++t) {
        const short* ks = Kb + (size_t)(kb0 + t * 16 + col) * DDIM + quad * 8;
        kfA[t][0] = *(const bf16x8*)ks;
        kfA[t][1] = *(const bf16x8*)(ks + 32);
    }

    for (int kb = 0; kb < BPW; ++kb) {
        const int kbase = kb0 + kb * KBLK;
        const bool has_next = (kb + 1 < BPW);

        // ---- (A) next-iteration K prefetch: issued before this iter's stores ----
        bf16x8 kfB[4][2];
        if (has_next) {
            const int kn = kbase + KBLK;
            #pragma unroll
            for (int t = 0; t < 4; ++t) {
                const short* ks = Kb + (size_t)(kn + t * 16 + col) * DDIM + quad * 8;
                kfB[t][0] = *(const bf16x8*)ks;
                kfB[t][1] = *(const bf16x8*)(ks + 32);
            }
        }

        // ---- (A2) current-iteration VT + mask loads (also before the stores) ----
        bf16x8 vt[2][4];
        #pragma unroll
        for (int c = 0; c < 2; ++c)
            #pragma unroll
            for (int dt = 0; dt < 4; ++dt)
                vt[c][dt] = *(const bf16x8*)(VTb + (size_t)(dt * 16 + col) * SDIM + kbase + c * 32 + quad * 8);
        int4 mq[4];
        #pragma unroll
        for (int t = 0; t < 4; ++t)
            mq[t] = *(const int4*)(Mb + kbase + t * 16 + quad * 4);

        // ---- (B/C/D) QK^T -> p -> Filt store + bf16 park ----
        // QK^T waits on kfA (loaded last iteration, before last iteration's
        // stores) -> the wait drains only stores from two iterations back.
        #pragma unroll
        for (int t = 0; t < 4; ++t) {
            f32x4 acc = {0.f, 0.f, 0.f, 0.f};
            acc = __builtin_amdgcn_mfma_f32_16x16x32_bf16(kfA[t][0], aq[0], acc, 0, 0, 0);
            acc = __builtin_amdgcn_mfma_f32_16x16x32_bf16(kfA[t][1], aq[1], acc, 0, 0, 0);
            f32x4 p4;
            p4[0] = mq[t].x ? 0.0f : __expf(acc[0]) * invl;
            p4[1] = mq[t].y ? 0.0f : __expf(acc[1]) * invl;
            p4[2] = mq[t].z ? 0.0f : __expf(acc[2]) * invl;
            p4[3] = mq[t].w ? 0.0f : __expf(acc[3]) * invl;
            // 4 consecutive keys of one query row -> dwordx4 nontemporal store.
            f32x4* fdst = (f32x4*)&Filtb[(size_t)(qt * 64 + w * 16 + col) * SDIM + kbase + t * 16 + quad * 4];
            __builtin_nontemporal_store(p4, fdst);
            bf16x4 pb;
            pb[0] = f2bf(p4[0]); pb[1] = f2bf(p4[1]);
            pb[2] = f2bf(p4[2]); pb[3] = f2bf(p4[3]);
            *(bf16x4*)&Plds[w][col][t * 16 + quad * 4] = pb;   // per-wave park
        }

        // ---- (E) O += P * V: vt was loaded BEFORE the stores above, so this
        // wait is vmcnt(4) (stores stay in flight), not a drain.
        #pragma unroll
        for (int c = 0; c < 2; ++c) {
            bf16x8 ap = *(const bf16x8*)&Plds[w][col][c * 32 + quad * 8];
            #pragma unroll
            for (int dt = 0; dt < 4; ++dt)
                Oacc[dt] = __builtin_amdgcn_mfma_f32_16x16x32_bf16(ap, vt[c][dt], Oacc[dt], 0, 0, 0);
        }

        // ---- (F) rotate K buffer ----
        if (has_next) {
            #pragma unroll
            for (int t = 0; t < 4; ++t) { kfA[t][0] = kfB[t][0]; kfA[t][1] = kfB[t][1]; }
        }
    }

    // per-split context partial (plain stores; reduced by attn_ctx)
    float* Ob = Opart + ((size_t)sp * NROWS + (size_t)b * SDIM) * DDIM;
    #pragma unroll
    for (int dt = 0; dt < 4; ++dt) {
        #pragma unroll
        for (int r = 0; r < 4; ++r)
            Ob[(size_t)(qt * 64 + w * 16 + quad * 4 + r) * DDIM + dt * 16 + col] = Oacc[dt][r];
    }
}

// ===================== K3: reduce 4 split-partials -> Ctx =====================
__global__ __launch_bounds__(256)
void attn_ctx(const float* __restrict__ Opart, float* __restrict__ Ctx)
{
    const size_t t = (size_t)blockIdx.x * 256 + threadIdx.x;   // one float4 each
    const size_t Qn = (size_t)NROWS * DDIM / 4;                // 262144
    const f32x4* op = (const f32x4*)Opart;
    f32x4 s0 = op[t] + op[Qn + t];
    f32x4 s1 = op[2 * Qn + t] + op[3 * Qn + t];
    ((f32x4*)Ctx)[t] = s0 + s1;
}

extern "C" void kernel_launch(void* const* d_in, const int* in_sizes, int n_in,
                              void* d_out, int out_size, void* d_ws, size_t ws_size,
                              hipStream_t stream) {
    // setup_inputs order: key, query, value, query_attention_mask
    const float* Kg = (const float*)d_in[0];
    const float* Qg = (const float*)d_in[1];
    const float* Vg = (const float*)d_in[2];
    const int*   Mg = (const int*)d_in[3];
    float* Ctx  = (float*)d_out;                                   // [8,2048,64]
    float* Filt = (float*)d_out + (size_t)BATCH * SDIM * DDIM;     // [8,2048,2048]

    // workspace: Kbf 2 MB | VTbf 2 MB | part 256 KB | Opart 16 MB
    short* Kbf  = (short*)d_ws;                                    // [8][2048][64] bf16
    short* VTbf = Kbf + (size_t)BATCH * SDIM * DDIM;               // [8][64][2048] bf16
    float* part = (float*)(VTbf + (size_t)BATCH * DDIM * SDIM);    // [4][16384]
    float* Opart = part + (size_t)KSPLIT * NROWS;                  // [4][16384][64]

    attn_prep<<<dim3(BATCH * NBLK), dim3(256), 0, stream>>>(Kg, Vg, Kbf, VTbf);
    // 8 batches x 32 qtiles x 4 key-splits = 1024 WGs (sp = wg>>8 decode)
    attn_stats<<<dim3(BATCH * NBLK * KSPLIT), dim3(256), 0, stream>>>(Kbf, Qg, Mg, part);
    attn_emit<<<dim3(BATCH * NBLK * KSPLIT), dim3(256), 0, stream>>>(Kbf, VTbf, Qg, Mg, part, Opart, Filt);
    attn_ctx<<<dim3(NROWS * DDIM / 4 / 256), dim3(256), 0, stream>>>(Opart, Ctx);
}

// Round 4
// 240.459 us; speedup vs baseline: 1.2125x; 1.0067x over previous
//
#include <hip/hip_runtime.h>
#include <math.h>

// Fused self-attention, B=8, S=2048, D=64 fp32; outputs context [8,2048,64] and
// full attention filter [8,2048,2048].
//
// Round-10: REVERT to the round-7 structure (best measured: 167 us), which is
// the anchor. Rounds 8-9 (register prefetch pipeline; Opart+ctx reduction)
// regressed end-to-end (291/242 us) despite better profiled emit times -> both
// rolled back. Single delta vs round-7: bf16 -> fp16 fragments.
//   - f16 MFMA runs at the bf16 rate; fp16 mantissa (10b vs 7b) cuts
//     conversion error ~8x (absmax margin), and native (_Float16) casts are
//     one v_cvt_f16_f32 instead of the 4-op manual RNE bf16 pack.
//   - Structure: 3 kernels, no barriers in hot kernels, direct-global
//     fragment loads (K/VT are L2-resident), swapped-operand QK^T
//     (C[key][query] -> dwordx4 nontemporal Filt stores), per-wave LDS P park,
//     Ctx via unsafeAtomicAdd (zeroed in prep).
//   - softmax temperature folded into Q->fp16 conversion (x2^-3 exact).

typedef _Float16 f16x8 __attribute__((ext_vector_type(8)));
typedef _Float16 f16x4 __attribute__((ext_vector_type(4)));
typedef float f32x4 __attribute__((ext_vector_type(4)));

#define BATCH 8
#define SDIM 2048
#define DDIM 64
#define KBLK 64
#define NBLK (SDIM / KBLK)      // 32
#define KSPLIT 4
#define BPW (NBLK / KSPLIT)     // 8 key-blocks per WG
#define NROWS (BATCH * SDIM)    // 16384
#define SCALE 0.125f
#define KSTR 72                 // LDS row stride in shorts (144 B, 16B-aligned)

__device__ __forceinline__ float fidx(const float4& v, int i) {
    return ((const float*)&v)[i];
}

// ======== K0: K->fp16, V->fp16 transposed, zero Ctx.  256 WGs ========
__global__ __launch_bounds__(256, 4)
void attn_prep(const float* __restrict__ Kg, const float* __restrict__ Vg,
               short* __restrict__ Kbf, short* __restrict__ VTbf,
               float* __restrict__ Ctx)
{
    __shared__ short VTlds[DDIM][KSTR];

    const int wg = blockIdx.x;           // 256 = 8 batches x 32 key-blocks
    const int b = wg & 7;
    const int kbase = (wg >> 3) * KBLK;
    const int tid = threadIdx.x;

    const float* Kb = Kg + (size_t)b * SDIM * DDIM;
    const float* Vb = Vg + (size_t)b * SDIM * DDIM;

    // K convert: thread t -> key=t>>2, 16 d's
    {
        const int key = tid >> 2, doff = (tid & 3) * 16;
        const float* src = Kb + (size_t)(kbase + key) * DDIM + doff;
        float4 f0 = *(const float4*)(src);
        float4 f1 = *(const float4*)(src + 4);
        float4 f2 = *(const float4*)(src + 8);
        float4 f3 = *(const float4*)(src + 12);
        f16x8 p0, p1;
        p0[0]=(_Float16)f0.x; p0[1]=(_Float16)f0.y; p0[2]=(_Float16)f0.z; p0[3]=(_Float16)f0.w;
        p0[4]=(_Float16)f1.x; p0[5]=(_Float16)f1.y; p0[6]=(_Float16)f1.z; p0[7]=(_Float16)f1.w;
        p1[0]=(_Float16)f2.x; p1[1]=(_Float16)f2.y; p1[2]=(_Float16)f2.z; p1[3]=(_Float16)f2.w;
        p1[4]=(_Float16)f3.x; p1[5]=(_Float16)f3.y; p1[6]=(_Float16)f3.z; p1[7]=(_Float16)f3.w;
        short* dst = Kbf + ((size_t)b * SDIM + kbase + key) * DDIM + doff;
        *(f16x8*)dst = p0;
        *(f16x8*)(dst + 8) = p1;
    }

    // V transpose via LDS: thread t loads 4 keys x 4 d's, writes transposed
    {
        const int sv_d0 = (tid & 15) * 4, sv_k0 = (tid >> 4) * 4;
        float4 vreg[4];
        #pragma unroll
        for (int i = 0; i < 4; ++i)
            vreg[i] = *(const float4*)(Vb + (size_t)(kbase + sv_k0 + i) * DDIM + sv_d0);
        #pragma unroll
        for (int dd = 0; dd < 4; ++dd) {
            f16x4 pv;
            pv[0] = (_Float16)fidx(vreg[0], dd);
            pv[1] = (_Float16)fidx(vreg[1], dd);
            pv[2] = (_Float16)fidx(vreg[2], dd);
            pv[3] = (_Float16)fidx(vreg[3], dd);
            *(f16x4*)&VTlds[sv_d0 + dd][sv_k0] = pv;
        }
    }
    __syncthreads();
    {
        const int d = tid >> 2, koff = (tid & 3) * 16;
        f16x8 a = *(const f16x8*)&VTlds[d][koff];
        f16x8 c = *(const f16x8*)&VTlds[d][koff + 8];
        short* dst = VTbf + ((size_t)b * DDIM + d) * SDIM + kbase + koff;
        *(f16x8*)dst = a;
        *(f16x8*)(dst + 8) = c;
    }

    // zero this WG's 16 KB slice of Ctx (4 MB / 256 WGs)
    {
        float4* dst = (float4*)Ctx + (size_t)wg * 1024;
        for (int i = tid; i < 1024; i += 256) dst[i] = make_float4(0.f, 0.f, 0.f, 0.f);
    }
}

// ============ K1: partial row sums (no LDS, no barriers) ============
// Swapped MFMA: C[key=quad*4+r][query=col]; lsum is per-lane scalar.
__global__ __launch_bounds__(256, 4)
void attn_stats(const short* __restrict__ Kbf, const float* __restrict__ Qg,
                const int* __restrict__ Mg, float* __restrict__ part)
{
    const int wg = blockIdx.x;
    const int b = wg & 7;
    const int qt = (wg >> 3) & 31;
    const int sp = wg >> 8;
    const int tid = threadIdx.x;
    const int w = tid >> 6, lane = tid & 63, col = lane & 15, quad = lane >> 4;

    // persistent Q fragment (used as B operand); temperature folded in (exact)
    f16x8 aq[2];
    {
        const float* qsrc = Qg + ((size_t)b * SDIM + qt * 64 + w * 16 + col) * DDIM + quad * 8;
        #pragma unroll
        for (int c = 0; c < 2; ++c) {
            float4 f0 = *(const float4*)(qsrc + c * 32);
            float4 f1 = *(const float4*)(qsrc + c * 32 + 4);
            f16x8 a;
            a[0]=(_Float16)(f0.x*SCALE); a[1]=(_Float16)(f0.y*SCALE); a[2]=(_Float16)(f0.z*SCALE); a[3]=(_Float16)(f0.w*SCALE);
            a[4]=(_Float16)(f1.x*SCALE); a[5]=(_Float16)(f1.y*SCALE); a[6]=(_Float16)(f1.z*SCALE); a[7]=(_Float16)(f1.w*SCALE);
            aq[c] = a;
        }
    }

    const int kb0 = sp * BPW * KBLK;
    const short* Kb = Kbf + (size_t)b * SDIM * DDIM;
    const int*   Mb = Mg + (size_t)b * SDIM;

    float lsum = 0.0f;
    for (int kb = 0; kb < BPW; ++kb) {
        const int kbase = kb0 + kb * KBLK;
        f16x8 kf[4][2];
        #pragma unroll
        for (int t = 0; t < 4; ++t) {
            const short* ks = Kb + (size_t)(kbase + t * 16 + col) * DDIM + quad * 8;
            kf[t][0] = *(const f16x8*)ks;
            kf[t][1] = *(const f16x8*)(ks + 32);
        }
        #pragma unroll
        for (int t = 0; t < 4; ++t) {
            f32x4 acc = {0.f, 0.f, 0.f, 0.f};
            acc = __builtin_amdgcn_mfma_f32_16x16x32_f16(kf[t][0], aq[0], acc, 0, 0, 0);
            acc = __builtin_amdgcn_mfma_f32_16x16x32_f16(kf[t][1], aq[1], acc, 0, 0, 0);
            int4 mq = *(const int4*)(Mb + kbase + t * 16 + quad * 4);
            lsum += mq.x ? 0.0f : __expf(acc[0]);
            lsum += mq.y ? 0.0f : __expf(acc[1]);
            lsum += mq.z ? 0.0f : __expf(acc[2]);
            lsum += mq.w ? 0.0f : __expf(acc[3]);
        }
    }

    // each lane has a quarter of this query's keys; sum across quads
    lsum += __shfl_xor(lsum, 16);
    lsum += __shfl_xor(lsum, 32);
    if (quad == 0)
        part[(size_t)sp * NROWS + (size_t)b * SDIM + qt * 64 + w * 16 + col] = lsum;
}

// ======= K2: emit filter + accumulate context (no barriers) =======
__global__ __launch_bounds__(256, 4)
void attn_emit(const short* __restrict__ Kbf, const short* __restrict__ VTbf,
               const float* __restrict__ Qg, const int* __restrict__ Mg,
               const float* __restrict__ part, float* __restrict__ Ctx,
               float* __restrict__ Filt)
{
    __shared__ short Plds[4][16][KSTR];   // per-wave fp16 P tile [q=16][k=64]

    const int wg = blockIdx.x;
    const int b = wg & 7;
    const int qt = (wg >> 3) & 31;
    const int sp = wg >> 8;
    const int tid = threadIdx.x;
    const int w = tid >> 6, lane = tid & 63, col = lane & 15, quad = lane >> 4;

    const int*   Mb = Mg + (size_t)b * SDIM;
    const short* Kb = Kbf + (size_t)b * SDIM * DDIM;
    const short* VTb = VTbf + (size_t)b * DDIM * SDIM;
    float* Ctxb  = Ctx  + (size_t)b * SDIM * DDIM;
    float* Filtb = Filt + (size_t)b * SDIM * SDIM;

    f16x8 aq[2];
    {
        const float* qsrc = Qg + ((size_t)b * SDIM + qt * 64 + w * 16 + col) * DDIM + quad * 8;
        #pragma unroll
        for (int c = 0; c < 2; ++c) {
            float4 f0 = *(const float4*)(qsrc + c * 32);
            float4 f1 = *(const float4*)(qsrc + c * 32 + 4);
            f16x8 a;
            a[0]=(_Float16)(f0.x*SCALE); a[1]=(_Float16)(f0.y*SCALE); a[2]=(_Float16)(f0.z*SCALE); a[3]=(_Float16)(f0.w*SCALE);
            a[4]=(_Float16)(f1.x*SCALE); a[5]=(_Float16)(f1.y*SCALE); a[6]=(_Float16)(f1.z*SCALE); a[7]=(_Float16)(f1.w*SCALE);
            aq[c] = a;
        }
    }

    // merge folded in: invl for THIS lane's query row (query = col)
    float invl;
    {
        const size_t row = (size_t)b * SDIM + qt * 64 + w * 16 + col;
        invl = 1.0f / (part[row] + part[NROWS + row] +
                       part[2 * NROWS + row] + part[3 * NROWS + row]);
    }

    const int kb0 = sp * BPW * KBLK;

    f32x4 Oacc[4];
    #pragma unroll
    for (int dt = 0; dt < 4; ++dt) Oacc[dt] = (f32x4){0.f, 0.f, 0.f, 0.f};

    for (int kb = 0; kb < BPW; ++kb) {
        const int kbase = kb0 + kb * KBLK;

        // ---- QK^T (swapped): lane -> query=col, keys kbase+t*16+quad*4+r ----
        f16x8 kf[4][2];
        #pragma unroll
        for (int t = 0; t < 4; ++t) {
            const short* ks = Kb + (size_t)(kbase + t * 16 + col) * DDIM + quad * 8;
            kf[t][0] = *(const f16x8*)ks;
            kf[t][1] = *(const f16x8*)(ks + 32);
        }
        #pragma unroll
        for (int t = 0; t < 4; ++t) {
            f32x4 acc = {0.f, 0.f, 0.f, 0.f};
            acc = __builtin_amdgcn_mfma_f32_16x16x32_f16(kf[t][0], aq[0], acc, 0, 0, 0);
            acc = __builtin_amdgcn_mfma_f32_16x16x32_f16(kf[t][1], aq[1], acc, 0, 0, 0);
            int4 mq = *(const int4*)(Mb + kbase + t * 16 + quad * 4);
            f32x4 p4;
            p4[0] = mq.x ? 0.0f : __expf(acc[0]) * invl;
            p4[1] = mq.y ? 0.0f : __expf(acc[1]) * invl;
            p4[2] = mq.z ? 0.0f : __expf(acc[2]) * invl;
            p4[3] = mq.w ? 0.0f : __expf(acc[3]) * invl;
            // 4 consecutive keys of one query row -> dwordx4 nontemporal store
            f32x4* fdst = (f32x4*)&Filtb[(size_t)(qt * 64 + w * 16 + col) * SDIM + kbase + t * 16 + quad * 4];
            __builtin_nontemporal_store(p4, fdst);
            f16x4 pb;
            pb[0] = (_Float16)p4[0]; pb[1] = (_Float16)p4[1];
            pb[2] = (_Float16)p4[2]; pb[3] = (_Float16)p4[3];
            *(f16x4*)&Plds[w][col][t * 16 + quad * 4] = pb;   // per-wave park
        }

        // ---- O += P * V (VT read direct from global; L2-resident) ----
        #pragma unroll
        for (int c = 0; c < 2; ++c) {
            f16x8 ap = *(const f16x8*)&Plds[w][col][c * 32 + quad * 8];
            #pragma unroll
            for (int dt = 0; dt < 4; ++dt) {
                const short* vs = VTb + (size_t)(dt * 16 + col) * SDIM + kbase + c * 32 + quad * 8;
                f16x8 bv = *(const f16x8*)vs;
                Oacc[dt] = __builtin_amdgcn_mfma_f32_16x16x32_f16(ap, bv, Oacc[dt], 0, 0, 0);
            }
        }
    }

    // accumulate partial context (4-way contention across key-splits)
    #pragma unroll
    for (int dt = 0; dt < 4; ++dt) {
        #pragma unroll
        for (int r = 0; r < 4; ++r) {
            unsafeAtomicAdd(&Ctxb[(size_t)(qt * 64 + w * 16 + quad * 4 + r) * DDIM + dt * 16 + col],
                            Oacc[dt][r]);
        }
    }
}

extern "C" void kernel_launch(void* const* d_in, const int* in_sizes, int n_in,
                              void* d_out, int out_size, void* d_ws, size_t ws_size,
                              hipStream_t stream) {
    // setup_inputs order: key, query, value, query_attention_mask
    const float* Kg = (const float*)d_in[0];
    const float* Qg = (const float*)d_in[1];
    const float* Vg = (const float*)d_in[2];
    const int*   Mg = (const int*)d_in[3];
    float* Ctx  = (float*)d_out;                                   // [8,2048,64]
    float* Filt = (float*)d_out + (size_t)BATCH * SDIM * DDIM;     // [8,2048,2048]

    // workspace: Kbf 2 MB | VTbf 2 MB | part 256 KB
    short* Kbf  = (short*)d_ws;                                    // [8][2048][64] fp16
    short* VTbf = Kbf + (size_t)BATCH * SDIM * DDIM;               // [8][64][2048] fp16
    float* part = (float*)(VTbf + (size_t)BATCH * DDIM * SDIM);    // [4][16384]

    attn_prep<<<dim3(BATCH * NBLK), dim3(256), 0, stream>>>(Kg, Vg, Kbf, VTbf, Ctx);
    // 8 batches x 32 qtiles x 4 key-splits = 1024 WGs (sp = wg>>8 decode)
    attn_stats<<<dim3(BATCH * NBLK * KSPLIT), dim3(256), 0, stream>>>(Kbf, Qg, Mg, part);
    attn_emit<<<dim3(BATCH * NBLK * KSPLIT), dim3(256), 0, stream>>>(Kbf, VTbf, Qg, Mg, part, Ctx, Filt);
}